// Round 7
// baseline (359.183 us; speedup 1.0000x reference)
//
#include <hip/hip_runtime.h>
#include <cstdint>
#include <cstddef>

#define S_LEN 2048
#define DIM_   2048
#define NH   16
#define NKV  8
#define HD   128

typedef __attribute__((ext_vector_type(8))) __bf16 bf16x8;
typedef __attribute__((ext_vector_type(4))) float  f32x4;

typedef const __attribute__((address_space(1))) void* gptr_t;
typedef __attribute__((address_space(3))) void*       sptr_t;

static __device__ __forceinline__ float bf2f(unsigned short u) {
  union { unsigned int i; float f; } v; v.i = ((unsigned int)u) << 16; return v.f;
}
static __device__ __forceinline__ unsigned short f2bf(float f) {
  union { float f; unsigned int i; } v; v.f = f;
  unsigned int u = v.i;
  unsigned int r = (u + 0x7FFFu + ((u >> 16) & 1u)) >> 16;
  return (unsigned short)r;
}
static __device__ __forceinline__ unsigned int pack2bf(float lo, float hi) {
  return ((unsigned int)f2bf(hi) << 16) | (unsigned int)f2bf(lo);
}

// scale(1/sqrt(128)) * log2(e) — folded into q so softmax uses exp2 directly
#define QSCALE 0.12751744f

// ---------------- prep: x->bf16 convert + 4 weight transpose-converts ----------------
__global__ void k_prep(const float* __restrict__ x, unsigned short* __restrict__ xb,
                       const float* __restrict__ wq, const float* __restrict__ wk,
                       const float* __restrict__ wv, const float* __restrict__ wo,
                       unsigned short* __restrict__ wqkvT, unsigned short* __restrict__ woT) {
  int bid = blockIdx.x;
  if (bid < 8192) {
    int i = bid * 256 + threadIdx.x;
    float4 v = ((const float4*)x)[i];
    ushort4 o; o.x = f2bf(v.x); o.y = f2bf(v.y); o.z = f2bf(v.z); o.w = f2bf(v.w);
    ((ushort4*)xb)[i] = o;
    return;
  }
  bid -= 8192;
  const float* src; unsigned short* dst; int N, ntx;
  if (bid < 4096)      { src = wq; dst = wqkvT;                       N = 2048; ntx = 64; }
  else if (bid < 6144) { bid -= 4096; src = wk; dst = wqkvT + (size_t)2048 * 2048; N = 1024; ntx = 32; }
  else if (bid < 8192) { bid -= 6144; src = wv; dst = wqkvT + (size_t)3072 * 2048; N = 1024; ntx = 32; }
  else                 { bid -= 8192; src = wo; dst = woT;            N = 2048; ntx = 64; }
  const int K = 2048;
  __shared__ float tile[32][33];
  int lx = threadIdx.x & 31, ly = threadIdx.x >> 5; // 32 x 8
  int r0 = (bid / ntx) * 32, c0 = (bid % ntx) * 32;
  #pragma unroll
  for (int r = 0; r < 32; r += 8)
    tile[ly + r][lx] = src[(size_t)(r0 + ly + r) * N + c0 + lx];
  __syncthreads();
  #pragma unroll
  for (int r = 0; r < 32; r += 8)
    dst[(size_t)(c0 + ly + r) * K + r0 + lx] = f2bf(tile[lx][ly + r]);
}

// ------------- GEMM: C(MxN) = A(MxK) * BT(NxK)^T, bf16 in, fp32 acc -------------
// BK=64, XOR-swizzled LDS via source permutation (conflict-free, measured 0).
// __launch_bounds__(256,2): VGPR cap 256 so all fragments stay live.
// MODE 1: store f32 natural C[m][n]
// MODE 3: fused QKV epilogue (q+RoPE*QSCALE | k+RoPE | v transposed).
template<int MODE>
__global__ __launch_bounds__(256, 2) void k_gemm_bt(
    const unsigned short* __restrict__ A, const unsigned short* __restrict__ BT,
    void* __restrict__ C, int N, int K,
    const float* __restrict__ fc, const float* __restrict__ fs,
    unsigned short* __restrict__ kb, unsigned short* __restrict__ vb) {
  __shared__ __align__(16) unsigned short Asm[128 * 64];
  __shared__ __align__(16) unsigned short Bsm[128 * 64];
  const int t = threadIdx.x;
  const int lane = t & 63, w = t >> 6;
  const int wm = (w >> 1) * 64, wn = (w & 1) * 64;
  const int col = lane & 15, quad = lane >> 4;
  const int m0 = blockIdx.y * 128, n0 = blockIdx.x * 128;

  f32x4 acc[4][4];
  #pragma unroll
  for (int i = 0; i < 4; i++)
    #pragma unroll
    for (int j = 0; j < 4; j++) acc[i][j] = (f32x4){0.f, 0.f, 0.f, 0.f};

  for (int kk = 0; kk < K; kk += 64) {
    #pragma unroll
    for (int r = 0; r < 4; ++r) {
      int c = t + r * 256;
      int c0 = (t & ~63) + r * 256;   // wave-uniform chunk base
      int row = c >> 3;
      int kcs = (c & 7) ^ (row & 7);  // source permutation = target swizzle
      const unsigned short* gA = A + (size_t)(m0 + row) * K + kk + kcs * 8;
      const unsigned short* gB = BT + (size_t)(n0 + row) * K + kk + kcs * 8;
      __builtin_amdgcn_global_load_lds((gptr_t)gA, (sptr_t)(&Asm[c0 * 8]), 16, 0, 0);
      __builtin_amdgcn_global_load_lds((gptr_t)gB, (sptr_t)(&Bsm[c0 * 8]), 16, 0, 0);
    }
    __syncthreads();
    #pragma unroll
    for (int kc2 = 0; kc2 < 2; kc2++) {
      bf16x8 af[4], bf[4];
      #pragma unroll
      for (int mi = 0; mi < 4; mi++) {
        int rowA = wm + mi * 16 + col;
        af[mi] = *(const bf16x8*)(&Asm[rowA * 64 + (((kc2 * 4 + quad) ^ (col & 7)) * 8)]);
      }
      #pragma unroll
      for (int ni = 0; ni < 4; ni++) {
        int rowB = wn + ni * 16 + col;
        bf[ni] = *(const bf16x8*)(&Bsm[rowB * 64 + (((kc2 * 4 + quad) ^ (col & 7)) * 8)]);
      }
      #pragma unroll
      for (int mi = 0; mi < 4; mi++)
        #pragma unroll
        for (int ni = 0; ni < 4; ni++)
          acc[mi][ni] = __builtin_amdgcn_mfma_f32_16x16x32_bf16(af[mi], bf[ni], acc[mi][ni], 0, 0, 0);
    }
    __syncthreads();
  }

  #pragma unroll
  for (int mi = 0; mi < 4; mi++) {
    int row_base = m0 + wm + mi * 16 + quad * 4;
    #pragma unroll
    for (int ni = 0; ni < 4; ni++) {
      int col_g = n0 + wn + ni * 16 + col;
      if (MODE == 1) {
        float* O = (float*)C;
        #pragma unroll
        for (int r = 0; r < 4; r++) O[(size_t)(row_base + r) * N + col_g] = acc[mi][ni][r];
      } else {  // MODE 3
        int region = col_g >> 10;  // 0,1: q ; 2: k ; 3: v
        if (region < 3) {
          int ri = (col_g & 127) >> 1;
          float sgn = (col_g & 1) ? 1.f : -1.f;
          unsigned short* qO = (unsigned short*)C;
          #pragma unroll
          for (int r = 0; r < 4; r++) {
            int row = row_base + r;
            int s = row & (S_LEN - 1);
            float cv = fc[s * 64 + ri], sv = fs[s * 64 + ri];
            float val = acc[mi][ni][r];
            float other = __shfl_xor(val, 1);
            float res = val * cv + sgn * other * sv;
            if (region < 2) qO[(size_t)row * 2048 + col_g] = f2bf(res * QSCALE);
            else            kb[(size_t)row * 1024 + (col_g - 2048)] = f2bf(res);
          }
        } else {
          int n_local = col_g - 3072;
          int b = row_base >> 11, s = row_base & (S_LEN - 1);
          int kvh = n_local >> 7, d = n_local & (HD - 1);
          ushort4 o4;
          o4.x = f2bf(acc[mi][ni][0]); o4.y = f2bf(acc[mi][ni][1]);
          o4.z = f2bf(acc[mi][ni][2]); o4.w = f2bf(acc[mi][ni][3]);
          *(ushort4*)(&vb[((size_t)((b * NKV + kvh) * HD + d)) * S_LEN + s]) = o4;
        }
      }
    }
  }
}

// ---------------- Flash attention, causal, GQA-shared K/V, S^T scheme ----------------
// 1024-thread blocks (16 waves): waves 0-3 = head 2g @ q-tile y, 4-7 = head 2g+1 @ y,
// 8-11 = head 2g @ 31-y, 12-15 = head 2g+1 @ 31-y. One K/V staging serves all.
// S^T = K*Q^T (operand-swapped MFMA): queries live in C COLUMNS -> per-lane scalar
// m/l/alpha (2 shuffles per reduction), and P^T B-operand is built with 16
// ds_bpermute shuffles instead of an LDS round trip. O^T layout -> ushort4 stores.
#define KLD 136   // 128 + 8
#define VLD 72    // 64 + 8
__global__ __launch_bounds__(1024, 4) void k_attn(
    const unsigned short* __restrict__ q, const unsigned short* __restrict__ k,
    const unsigned short* __restrict__ vT, unsigned short* __restrict__ ao) {
  __shared__ __align__(16) unsigned short Ksm[64 * KLD];   // 17408 B
  __shared__ __align__(16) unsigned short Vsm[128 * VLD];  // 18432 B
  const int t = threadIdx.x;
  const int lane = t & 63, w = t >> 6;        // 16 waves
  const int col = lane & 15, quad = lane >> 4;
  const int g = blockIdx.x;                   // b*NKV + kvh
  const int b = g >> 3, kvh = g & 7;
  const int h = kvh * 2 + ((w >> 2) & 1);     // this wave's head
  const int y = blockIdx.y;                   // 0..15
  const int my_qt = (w < 8) ? y : (31 - y);
  const int qrow = my_qt * 64 + (w & 3) * 16; // this wave's 16 query rows
  const int qg = qrow + col;                  // this lane's query (S^T: q = C column)

  bf16x8 qf[4];
  const size_t qbase = ((size_t)(b * S_LEN) + qg) * DIM_ + h * HD;
  #pragma unroll
  for (int kc = 0; kc < 4; kc++) qf[kc] = *(const bf16x8*)(q + qbase + kc * 32 + quad * 8);

  f32x4 o[8];   // O^T[d][q]: row d = dt*16 + quad*4 + r, col q = this lane's query
  #pragma unroll
  for (int i = 0; i < 8; i++) o[i] = (f32x4){0.f, 0.f, 0.f, 0.f};
  float m_i = -1e30f, l_i = 0.f;

  // P^T exchange source lanes (fixed per lane): B-dword dw pulls packed regs of
  // sub-tile nt=2*kc2+(quad>>1) from lane (2*(quad&1)+(dw>>1))*16+col.
  const int ls0 = ((quad & 1) * 2) * 16 + col;
  const int ls1 = ls0 + 16;
  const bool hi_nt = (quad >> 1) != 0;

  const int nkt = 32 - y;   // covers the longest group (my_qt = 31-y)
  for (int kt = 0; kt < nkt; ++kt) {
    // stage K tile (64 keys x 128 d) and V^T tile (128 d x 64 keys): 1 uint4
    // per thread per matrix (1024 threads)
    { int i = t >> 4, dc = t & 15;
      *(uint4*)(&Ksm[i * KLD + dc * 8]) =
          *(const uint4*)(k + ((size_t)(b * S_LEN + kt * 64 + i)) * (NKV * HD) + kvh * HD + dc * 8);
      int d = t >> 3, kc2 = t & 7;
      *(uint4*)(&Vsm[d * VLD + kc2 * 8]) =
          *(const uint4*)(vT + ((size_t)((b * NKV + kvh) * HD + d)) * S_LEN + kt * 64 + kc2 * 8);
    }
    __syncthreads();

    if (kt <= my_qt) {   // wave-uniform causal range
      // S^T tile: D[key][query], key = nt*16 + quad*4 + r, query = col
      float p[4][4];
      #pragma unroll
      for (int nt = 0; nt < 4; nt++) {
        f32x4 s_acc = (f32x4){0.f, 0.f, 0.f, 0.f};
        #pragma unroll
        for (int kc = 0; kc < 4; kc++) {
          bf16x8 kf = *(const bf16x8*)(&Ksm[(nt * 16 + col) * KLD + kc * 32 + quad * 8]);
          s_acc = __builtin_amdgcn_mfma_f32_16x16x32_bf16(kf, qf[kc], s_acc, 0, 0, 0);
        }
        #pragma unroll
        for (int r = 0; r < 4; r++) p[nt][r] = s_acc[r];
      }
      if (kt == my_qt) {  // diagonal tile: causal mask (key > query)
        #pragma unroll
        for (int nt = 0; nt < 4; nt++) {
          int key = kt * 64 + nt * 16 + quad * 4;
          #pragma unroll
          for (int r = 0; r < 4; r++)
            if (key + r > qg) p[nt][r] = -1e30f;
        }
      }
      // per-lane scalar online softmax (query = col)
      float mx = p[0][0];
      #pragma unroll
      for (int nt = 0; nt < 4; nt++)
        #pragma unroll
        for (int r = 0; r < 4; r++) mx = fmaxf(mx, p[nt][r]);
      mx = fmaxf(mx, __shfl_xor(mx, 16));
      mx = fmaxf(mx, __shfl_xor(mx, 32));
      float mnew = fmaxf(m_i, mx);
      float alpha = exp2f(m_i - mnew);
      m_i = mnew;
      float rs = 0.f;
      #pragma unroll
      for (int nt = 0; nt < 4; nt++)
        #pragma unroll
        for (int r = 0; r < 4; r++) {
          float e = exp2f(p[nt][r] - mnew);
          p[nt][r] = e;
          rs += e;
        }
      rs += __shfl_xor(rs, 16);
      rs += __shfl_xor(rs, 32);
      l_i = l_i * alpha + rs;
      #pragma unroll
      for (int dt = 0; dt < 8; dt++)
        #pragma unroll
        for (int r = 0; r < 4; r++) o[dt][r] *= alpha;

      // pack P rows pairwise, then build P^T B-fragments via shuffles
      unsigned int pk[4][2];
      #pragma unroll
      for (int nt = 0; nt < 4; nt++) {
        pk[nt][0] = pack2bf(p[nt][0], p[nt][1]);
        pk[nt][1] = pack2bf(p[nt][2], p[nt][3]);
      }
      #pragma unroll
      for (int kc2 = 0; kc2 < 2; kc2++) {
        union { bf16x8 v; unsigned int d[4]; } pf;
        unsigned int a0 = (unsigned int)__shfl((int)pk[2 * kc2][0], ls0);
        unsigned int b0 = (unsigned int)__shfl((int)pk[2 * kc2 + 1][0], ls0);
        pf.d[0] = hi_nt ? b0 : a0;
        unsigned int a1 = (unsigned int)__shfl((int)pk[2 * kc2][1], ls0);
        unsigned int b1 = (unsigned int)__shfl((int)pk[2 * kc2 + 1][1], ls0);
        pf.d[1] = hi_nt ? b1 : a1;
        unsigned int a2 = (unsigned int)__shfl((int)pk[2 * kc2][0], ls1);
        unsigned int b2 = (unsigned int)__shfl((int)pk[2 * kc2 + 1][0], ls1);
        pf.d[2] = hi_nt ? b2 : a2;
        unsigned int a3 = (unsigned int)__shfl((int)pk[2 * kc2][1], ls1);
        unsigned int b3 = (unsigned int)__shfl((int)pk[2 * kc2 + 1][1], ls1);
        pf.d[3] = hi_nt ? b3 : a3;
        // O^T += V^T * P^T for this 32-key chunk
        #pragma unroll
        for (int dt = 0; dt < 8; dt++) {
          bf16x8 vf = *(const bf16x8*)(&Vsm[(dt * 16 + col) * VLD + kc2 * 32 + quad * 8]);
          o[dt] = __builtin_amdgcn_mfma_f32_16x16x32_bf16(vf, pf.v, o[dt], 0, 0, 0);
        }
      }
    }
    __syncthreads();
  }

  // epilogue: O^T -> ao[q][d], 4 consecutive d per lane per dt -> ushort4
  float inv = 1.f / l_i;
  #pragma unroll
  for (int dt = 0; dt < 8; dt++) {
    ushort4 o4;
    o4.x = f2bf(o[dt][0] * inv); o4.y = f2bf(o[dt][1] * inv);
    o4.z = f2bf(o[dt][2] * inv); o4.w = f2bf(o[dt][3] * inv);
    *(ushort4*)(&ao[((size_t)(b * S_LEN) + qg) * DIM_ + h * HD + dt * 16 + quad * 4]) = o4;
  }
}

extern "C" void kernel_launch(void* const* d_in, const int* in_sizes, int n_in,
                              void* d_out, int out_size, void* d_ws, size_t ws_size,
                              hipStream_t stream) {
  const float* x  = (const float*)d_in[0];
  const float* fc = (const float*)d_in[1];
  const float* fs = (const float*)d_in[2];
  const float* wq = (const float*)d_in[3];
  const float* wk = (const float*)d_in[4];
  const float* wv = (const float*)d_in[5];
  const float* wo = (const float*)d_in[6];
  float* out = (float*)d_out;

  char* ws = (char*)d_ws;
  const size_t MB = 1024 * 1024;
  unsigned short* xb    = (unsigned short*)(ws + 0 * MB);    // 4096x2048 bf16 (16 MiB)
  unsigned short* wqkvT = (unsigned short*)(ws + 16 * MB);   // 4096x2048      (16 MiB)
  unsigned short* woT   = (unsigned short*)(ws + 32 * MB);   // 2048x2048      (8 MiB)
  unsigned short* qb    = (unsigned short*)(ws + 40 * MB);   // 4096x2048      (16 MiB)
  unsigned short* kb    = (unsigned short*)(ws + 56 * MB);   // 4096x1024      (8 MiB)
  unsigned short* vT    = (unsigned short*)(ws + 64 * MB);   // (b,kvh,d,s)    (8 MiB)
  unsigned short* ao    = (unsigned short*)(ws + 72 * MB);   // 4096x2048      (16 MiB)

  // prep: convert x + transpose-convert all weights (one dispatch)
  k_prep<<<dim3(20480), dim3(256), 0, stream>>>(x, xb, wq, wk, wv, wo, wqkvT, woT);
  // fused QKV projection + RoPE (+q pre-scale) + V transpose
  k_gemm_bt<3><<<dim3(32, 32), dim3(256), 0, stream>>>(xb, wqkvT, (void*)qb, 4096, 2048, fc, fs, kb, vT);
  // attention (GQA-shared K/V staging, 1 block/CU, balanced, S^T scheme)
  k_attn<<<dim3(16, 16), dim3(1024), 0, stream>>>(qb, kb, vT, ao);
  // output projection (f32 out)
  k_gemm_bt<1><<<dim3(16, 32), dim3(256), 0, stream>>>(ao, woT, (void*)out, 2048, 2048, nullptr, nullptr, nullptr, nullptr);
}